// Round 4
// baseline (889.476 us; speedup 1.0000x reference)
//
#include <hip/hip_runtime.h>

// ST_Affine: affine_grid (align_corners=False) + grid_sample bilinear/zeros.
// B=16, C=64, H=W=256, fp32 in/out.
//
// V5: LDS-staged sampling. V1-V4 evidence: dur ~250us invariant to HBM bytes
// (867->391MB), gather inst count (4->2/px), occupancy (36->76%). 149 cyc/CU
// per {2 gathers + 1 store} iteration => bound by divergent-gather line
// processing in the TA/TCP (shear spreads each wave over ~6 source rows ->
// ~12-24 line transactions per gather, serialized).
// Fix: per 64x8 output tile, stage the source bbox (~16 rows x ~72 cols) into
// LDS with fully-coalesced loads; bilinear taps become ds_read2_b32 (x-addrs
// are stride~1 per lane -> ~conflict-free). Pixel slots/weights are channel-
// invariant -> computed once, reused over the 64-channel loop.
// Caps + block-uniform fallback to direct gathers keep correctness for any
// theta. XCD-contiguous swizzle (vertically-adjacent tiles share bbox rows
// in the same XCD's L2). NT stores.

constexpr int B = 16, C = 64, H = 256, W = 256;
constexpr int HW = H * W;        // 65536
constexpr int CHW = C * HW;      // 4194304

constexpr int WT = 64, HT = 8;               // output tile per block
constexpr int NYT = H / HT;                  // 32
constexpr int NXT = W / WT;                  // 4
constexpr int NBLK = B * NXT * NYT;          // 2048, %8==0
constexpr int NRCAP = 40;                    // staged rows cap
constexpr int WSCAP = 108;                   // staged cols cap (= LDS row stride)

__global__ __launch_bounds__(256) void st_affine_kernel(
    const float* __restrict__ x, const float* __restrict__ theta,
    float* __restrict__ out)
{
    __shared__ float smem[NRCAP * WSCAP];    // 17280 B -> 8 blocks/CU fits

    // XCD-contiguous swizzle; consecutive swz = vertically adjacent tiles.
    const int bid = blockIdx.x;
    constexpr int CHUNK = NBLK / 8;          // 256
    const int swz = (bid & 7) * CHUNK + (bid >> 3);

    const int ht   = swz & (NYT - 1);        // 0..31
    const int rest = swz >> 5;               // 0..63 = b*NXT + wt
    const int wt   = rest & (NXT - 1);
    const int b    = rest >> 2;
    const int h0 = ht * HT, w0 = wt * WT;

    const int tw = threadIdx.x & 63;         // column within tile
    const int tp = threadIdx.x >> 6;         // 0..3; rows tp and tp+4

    const float* th = theta + b * 6;
    const float t0 = th[0], t1 = th[1], t2 = th[2];
    const float t3 = th[3], t4 = th[4], t5 = th[5];

    // ---- tile source bounding box from the 4 output-tile corners ----
    const float gxl = (w0 + 0.5f)          * (2.0f / W) - 1.0f;
    const float gxr = (w0 + WT - 1 + 0.5f) * (2.0f / W) - 1.0f;
    const float gyt = (h0 + 0.5f)          * (2.0f / H) - 1.0f;
    const float gyb = (h0 + HT - 1 + 0.5f) * (2.0f / H) - 1.0f;

    auto mapix = [&](float gx, float gy) {
        return ((t0 * gx + t1 * gy + t2 + 1.0f) * (float)W - 1.0f) * 0.5f;
    };
    auto mapiy = [&](float gx, float gy) {
        return ((t3 * gx + t4 * gy + t5 + 1.0f) * (float)H - 1.0f) * 0.5f;
    };

    const float ixa = mapix(gxl, gyt), ixb = mapix(gxr, gyt),
                ixc = mapix(gxl, gyb), ixd = mapix(gxr, gyb);
    const float iya = mapiy(gxl, gyt), iyb = mapiy(gxr, gyt),
                iyc = mapiy(gxl, gyb), iyd = mapiy(gxr, gyb);

    const float ixmin = fminf(fminf(ixa, ixb), fminf(ixc, ixd));
    const float ixmax = fmaxf(fmaxf(ixa, ixb), fmaxf(ixc, ixd));
    const float iymin = fminf(fminf(iya, iyb), fminf(iyc, iyd));
    const float iymax = fmaxf(fmaxf(iya, iyb), fmaxf(iyc, iyd));

    // +-1 pad each side (kills fp-epsilon slot risk at tile borders)
    const int c0 = (int)floorf(ixmin) - 1;
    const int r0 = (int)floorf(iymin) - 1;
    const int WS = (int)floorf(ixmax) - c0 + 3;   // cols staged
    const int NR = (int)floorf(iymax) - r0 + 3;   // rows staged

    // ---- per-pixel geometry (channel-invariant): 2 pixels per thread ----
    int   ldsbase[2];
    float w00[2], w01[2], w10[2], w11[2];
    // fallback gather state
    int   off00[2], off01[2], off10[2], off11[2];

#pragma unroll
    for (int p = 0; p < 2; ++p) {
        const int hh = tp + p * 4;
        const float gx = (w0 + tw + 0.5f) * (2.0f / W) - 1.0f;
        const float gy = (h0 + hh + 0.5f) * (2.0f / H) - 1.0f;

        const float ix = mapix(gx, gy);
        const float iy = mapiy(gx, gy);

        const float ix0f = floorf(ix);
        const float iy0f = floorf(iy);
        const float tx = ix - ix0f;
        const float ty = iy - iy0f;
        const int ix0 = (int)ix0f, iy0 = (int)iy0f;
        const int ix1 = ix0 + 1,   iy1 = iy0 + 1;

        const float vx0 = (ix0 >= 0 && ix0 < W) ? 1.0f : 0.0f;
        const float vx1 = (ix1 >= 0 && ix1 < W) ? 1.0f : 0.0f;
        const float vy0 = (iy0 >= 0 && iy0 < H) ? 1.0f : 0.0f;
        const float vy1 = (iy1 >= 0 && iy1 < H) ? 1.0f : 0.0f;

        w00[p] = (1.0f - tx) * (1.0f - ty) * vx0 * vy0;
        w01[p] = tx          * (1.0f - ty) * vx1 * vy0;
        w10[p] = (1.0f - tx) * ty          * vx0 * vy1;
        w11[p] = tx          * ty          * vx1 * vy1;

        // LDS slots (clamped; OOB corners have weight 0 so any slot is safe)
        const int sxs = min(max(ix0 - c0, 0), WSCAP - 2);
        const int sys = min(max(iy0 - r0, 0), NRCAP - 2);
        ldsbase[p] = sys * WSCAP + sxs;

        // fallback offsets (always-safe clamped gathers)
        const int cx0 = min(max(ix0, 0), W - 1);
        const int cx1 = min(max(ix1, 0), W - 1);
        const int cy0 = min(max(iy0, 0), H - 1);
        const int cy1 = min(max(iy1, 0), H - 1);
        off00[p] = cy0 * W + cx0;  off01[p] = cy0 * W + cx1;
        off10[p] = cy1 * W + cx0;  off11[p] = cy1 * W + cx1;
    }

    const float* __restrict__ xb = x + (size_t)b * CHW;
    float* __restrict__ ob = out + (size_t)b * CHW + (size_t)h0 * W + w0 + tw;

    if (NR > NRCAP || WS > WSCAP) {
        // ---- fallback: direct gather path (block-uniform; pathological theta) ----
        for (int c = 0; c < C; ++c) {
            const float* __restrict__ xc = xb + (size_t)c * HW;
            float* __restrict__ oc = ob + (size_t)c * HW;
#pragma unroll
            for (int p = 0; p < 2; ++p) {
                const float v = xc[off00[p]] * w00[p] + xc[off01[p]] * w01[p]
                              + xc[off10[p]] * w10[p] + xc[off11[p]] * w11[p];
                __builtin_nontemporal_store(v, oc + (tp + p * 4) * W);
            }
        }
        return;
    }

    // ---- main path: stage bbox per channel, sample from LDS ----
    for (int c = 0; c < C; ++c) {
        const float* __restrict__ xc = xb + (size_t)c * HW;
        float* __restrict__ oc = ob + (size_t)c * HW;

        if (c) __syncthreads();              // protect prev channel's reads
        // coalesced stage: rows k strided by tp (4), cols j strided by tw (64)
        for (int k = tp; k < NR; k += 4) {
            const int rs = min(max(r0 + k, 0), H - 1);
            const float* __restrict__ rowp = xc + (rs << 8);   // W=256
            float* __restrict__ dst = smem + k * WSCAP;
            for (int j = tw; j < WS; j += 64) {
                const int cs = min(max(c0 + j, 0), W - 1);
                dst[j] = rowp[cs];
            }
        }
        __syncthreads();

#pragma unroll
        for (int p = 0; p < 2; ++p) {
            const int bse = ldsbase[p];
            const float a0 = smem[bse];
            const float a1 = smem[bse + 1];
            const float a2 = smem[bse + WSCAP];
            const float a3 = smem[bse + WSCAP + 1];
            const float v = a0 * w00[p] + a1 * w01[p]
                          + a2 * w10[p] + a3 * w11[p];
            __builtin_nontemporal_store(v, oc + (tp + p * 4) * W);
        }
    }
}

extern "C" void kernel_launch(void* const* d_in, const int* in_sizes, int n_in,
                              void* d_out, int out_size, void* d_ws, size_t ws_size,
                              hipStream_t stream) {
    const float* x     = (const float*)d_in[0];
    const float* theta = (const float*)d_in[1];
    float* out = (float*)d_out;

    dim3 grid(NBLK), block(256);
    st_affine_kernel<<<grid, block, 0, stream>>>(x, theta, out);
}